// Round 1
// baseline (43835.754 us; speedup 1.0000x reference)
//
#include <hip/hip_runtime.h>
#include <hip/hip_cooperative_groups.h>

namespace cg = cooperative_groups;

typedef unsigned short u16;
typedef _Float16 half8 __attribute__((ext_vector_type(8)));
typedef float f32x4 __attribute__((ext_vector_type(4)));

#define SEQ 512
#define MB 32
#define HD 1024
#define ID 256
#define OD 256
#define MBHD (MB * HD)

__device__ __forceinline__ u16 f16b(float v) {
  union { _Float16 h; u16 u; } cv;
  cv.h = (_Float16)v;
  return cv.u;
}

struct GruP {
  const float *bh0, *bh1, *by;
  const u16 *X16, *WtA0, *WtB0, *WtC1, *WtD1, *WtY;
  float *h0f32, *h1f32, *z0, *z1;
  u16 *h016, *h116, *rh016, *rh116;
  float *out;
};

// Stage [MB][K] fp16 input (concat of two row-major sources at chunk granularity)
// into LDS with per-row XOR swizzle on 16B chunks (2-way bank aliasing = free).
__device__ __forceinline__ void stage_in(u16* sm,
                                         const u16* __restrict__ s1, int ld1, int K1,
                                         const u16* __restrict__ s2, int ld2, int K,
                                         int tid) {
  int chunks = K >> 3, c1 = K1 >> 3;
  int total = MB * chunks;
  for (int i = tid; i < total; i += 256) {
    int r = i / chunks, c = i - r * chunks;
    const u16* src = (c < c1) ? (s1 + (size_t)r * ld1 + (c << 3))
                              : (s2 + (size_t)r * ld2 + ((c - c1) << 3));
    int4 v = *(const int4*)src;
    int cs = c ^ (r & 7);
    *(int4*)(sm + (size_t)r * K + (cs << 3)) = v;
  }
}

// One wave computes partial [32 x 16] for its K-quarter. Wt is [N][K] fp16.
// A and B fragments both load 16B contiguous-K chunks -> identical k-permutation.
__device__ __forceinline__ void mm16(const u16* sm, const u16* __restrict__ Wt,
                                     int n0, int K, int wave, int lane,
                                     f32x4& a0, f32x4& a1) {
  int b = lane >> 4, rr = lane & 15;
  int sw = rr & 7;
  const u16* wrow = Wt + (size_t)(n0 + rr) * K + (b << 3);
  const u16* arow0 = sm + (size_t)rr * K;
  const u16* arow1 = sm + (size_t)(16 + rr) * K;
  int kbeg = wave * (K >> 2);
  int nst = K >> 7;  // (K/4)/32 k-steps
  for (int s = 0; s < nst; ++s) {
    int k0 = kbeg + (s << 5);
    int cidx = (k0 >> 3) + b;
    half8 A0 = *(const half8*)(arow0 + ((cidx ^ sw) << 3));
    half8 A1 = *(const half8*)(arow1 + ((cidx ^ sw) << 3));
    half8 Bf = *(const half8*)(wrow + k0);
    a0 = __builtin_amdgcn_mfma_f32_16x16x32_f16(A0, Bf, a0, 0, 0, 0);
    a1 = __builtin_amdgcn_mfma_f32_16x16x32_f16(A1, Bf, a1, 0, 0, 0);
  }
}

__global__ void __launch_bounds__(256, 1) gru_main(GruP p) {
  __shared__ __align__(16) u16 sm[MB * 2048];   // 128 KB staged input
  __shared__ float psum[4][MB][16];             // 8 KB cross-wave partials
  cg::grid_group grid = cg::this_grid();
  const int w = blockIdx.x, tid = threadIdx.x;
  const int wave = tid >> 6, lane = tid & 63;

  for (int t = 0; t <= SEQ + 1; ++t) {
    // ================= tick ALPHA: z,r gates (L0 step t | L1 step t-1) ========
    {
      bool act = false;
      int K = 0, K1 = 0, n0 = 0, ld1 = 0, ld2 = 0;
      const u16 *s1 = 0, *s2 = 0, *Wt = 0;
      const float *bias = 0, *hprev = 0;
      float* zout = 0; u16* rhout = 0;
      if (w < 128) {                       // L0: zr for step t, cols 16w of 2048
        if (t < SEQ) {
          act = true; K = ID + HD; K1 = ID; n0 = w << 4;
          s1 = p.X16 + (size_t)t * ID; ld1 = SEQ * ID;
          s2 = p.h016 + ((t + 1) & 1) * MBHD; ld2 = HD;
          Wt = p.WtA0; bias = p.bh0;
          zout = p.z0; rhout = p.rh016;
          hprev = p.h0f32 + ((t + 1) & 1) * MBHD;
        }
      } else {                             // L1: zr for step t-1
        if (t >= 1 && t <= SEQ) {
          int sst = t - 1;
          act = true; K = 2 * HD; K1 = HD; n0 = (w - 128) << 4;
          s1 = p.h016 + (sst & 1) * MBHD; ld1 = HD;   // h0_new(t-1)
          s2 = p.h116 + (t & 1) * MBHD;  ld2 = HD;    // h1 after step t-2
          Wt = p.WtC1; bias = p.bh1;
          zout = p.z1; rhout = p.rh116;
          hprev = p.h1f32 + (t & 1) * MBHD;
        }
      }
      if (act) {
        stage_in(sm, s1, ld1, K1, s2, ld2, K, tid);
        __syncthreads();
        f32x4 a0 = {0.f, 0.f, 0.f, 0.f}, a1 = {0.f, 0.f, 0.f, 0.f};
        mm16(sm, Wt, n0, K, wave, lane, a0, a1);
        int cc = lane & 15, rb = (lane >> 4) << 2;
#pragma unroll
        for (int i = 0; i < 4; ++i) {
          psum[wave][rb + i][cc] = a0[i];
          psum[wave][16 + rb + i][cc] = a1[i];
        }
        __syncthreads();
        for (int i = tid; i < MB * 16; i += 256) {
          int m = i >> 4, jc = i & 15, j = n0 + jc;
          float v = psum[0][m][jc] + psum[1][m][jc] + psum[2][m][jc] + psum[3][m][jc]
                    + bias[j];
          v = 1.f / (1.f + __expf(-v));
          if (j < HD) {
            zout[m * HD + j] = v;                       // z gate, fp32
          } else {
            int jr = j - HD;                            // r gate -> r*h_prev fp16
            rhout[m * HD + jr] = f16b(v * hprev[m * HD + jr]);
          }
        }
      }
    }
    grid.sync();
    // ================= tick BETA: g gate + h update (and y two steps back) ====
    {
      int role = 0;  // 0 idle, 1 g+update, 2 y
      int K = 0, K1 = 0, n0 = 0, ld1 = 0, ld2 = 0;
      const u16 *s1 = 0, *s2 = 0, *Wt = 0;
      const float *bias = 0, *hprev = 0, *zin = 0;
      float* houtf = 0; u16* hout16 = 0;
      if (w < 64) {                        // L0 g, step t
        if (t < SEQ) {
          role = 1; K = ID + HD; K1 = ID; n0 = w << 4;
          s1 = p.X16 + (size_t)t * ID; ld1 = SEQ * ID;
          s2 = p.rh016; ld2 = HD;
          Wt = p.WtB0; bias = p.bh0 + 2 * HD;
          hprev = p.h0f32 + ((t + 1) & 1) * MBHD;
          zin = p.z0;
          houtf = p.h0f32 + (t & 1) * MBHD;
          hout16 = p.h016 + (t & 1) * MBHD;
        }
      } else if (w < 80) {                 // y(t-2) = h1(t-2) @ Wy + by
        if (t >= 2) {
          role = 2; K = HD; K1 = HD; n0 = (w - 64) << 4;
          s1 = p.h116 + (t & 1) * MBHD; ld1 = HD;
          s2 = s1; ld2 = HD;
          Wt = p.WtY; bias = p.by;
        }
      } else if (w >= 128 && w < 192) {    // L1 g, step t-1
        if (t >= 1 && t <= SEQ) {
          role = 1; K = 2 * HD; K1 = HD; n0 = (w - 128) << 4;
          s1 = p.h016 + ((t - 1) & 1) * MBHD; ld1 = HD;
          s2 = p.rh116; ld2 = HD;
          Wt = p.WtD1; bias = p.bh1 + 2 * HD;
          hprev = p.h1f32 + (t & 1) * MBHD;
          zin = p.z1;
          houtf = p.h1f32 + ((t - 1) & 1) * MBHD;
          hout16 = p.h116 + ((t - 1) & 1) * MBHD;
        }
      }
      if (role) {
        stage_in(sm, s1, ld1, K1, s2, ld2, K, tid);
        __syncthreads();
        f32x4 a0 = {0.f, 0.f, 0.f, 0.f}, a1 = {0.f, 0.f, 0.f, 0.f};
        mm16(sm, Wt, n0, K, wave, lane, a0, a1);
        int cc = lane & 15, rb = (lane >> 4) << 2;
#pragma unroll
        for (int i = 0; i < 4; ++i) {
          psum[wave][rb + i][cc] = a0[i];
          psum[wave][16 + rb + i][cc] = a1[i];
        }
        __syncthreads();
        for (int i = tid; i < MB * 16; i += 256) {
          int m = i >> 4, jc = i & 15, j = n0 + jc;
          float v = psum[0][m][jc] + psum[1][m][jc] + psum[2][m][jc] + psum[3][m][jc]
                    + bias[j];
          if (role == 1) {
            float g = tanhf(v);
            float hp = hprev[m * HD + j];
            float z = zin[m * HD + j];
            float hn = z * hp + (1.f - z) * g;
            houtf[m * HD + j] = hn;
            hout16[m * HD + j] = f16b(hn);
          } else {
            p.out[((size_t)m * SEQ + (t - 2)) * OD + j] = v;
          }
        }
      }
    }
    grid.sync();
  }
  // Epilogue: final hidden states (both end in parity buffer 1 after step 511).
  if (w < MB) {
    const float* h0f = p.h0f32 + MBHD;
    const float* h1f = p.h1f32 + MBHD;
    for (int i = tid; i < 2 * HD; i += 256) {
      float v = (i < HD) ? h0f[w * HD + i] : h1f[w * HD + (i - HD)];
      p.out[(size_t)MB * SEQ * OD + (size_t)w * 2 * HD + i] = v;
    }
  }
}

// ---------------- prologue kernels ----------------

__global__ void convx_k(const float* __restrict__ x, u16* __restrict__ X16) {
  size_t i = (size_t)blockIdx.x * 256 + threadIdx.x;   // 524288 threads, 8 elems each
  const float4* s = (const float4*)x + i * 2;
  float4 a = s[0], b = s[1];
  u16 o[8];
  o[0] = f16b(a.x); o[1] = f16b(a.y); o[2] = f16b(a.z); o[3] = f16b(a.w);
  o[4] = f16b(b.x); o[5] = f16b(b.y); o[6] = f16b(b.z); o[7] = f16b(b.w);
  *(int4*)(X16 + i * 8) = *(const int4*)o;
}

__global__ void inith_k(const float* __restrict__ h0in,
                        float* h0f32, float* h1f32, u16* h016, u16* h116) {
  int idx = blockIdx.x * 256 + threadIdx.x;  // < 65536 : [b][l][h]
  float v = h0in[idx];
  int b = idx >> 11, rem = idx & 2047;
  int l = rem >> 10, h = rem & 1023;
  int o = MBHD + b * HD + h;                 // parity buffer 1
  if (l == 0) { h0f32[o] = v; h016[o] = f16b(v); }
  else        { h1f32[o] = v; h116[o] = f16b(v); }
}

// Build [N][K] fp16 transposed weight blocks (K = concat of Wx rows then Wh rows).
__global__ void wtrans_k(const float* __restrict__ Wx0, const float* __restrict__ Wh0,
                         const float* __restrict__ Wx1, const float* __restrict__ Wh1,
                         const float* __restrict__ Wy,
                         u16* A0, u16* B0, u16* C1, u16* D1, u16* Y) {
  __shared__ u16 tile[32][34];
  int mid = blockIdx.z;
  int K, N, k1, coloff, ld; const float *b1, *b2; u16* dst;
  if (mid == 0)      { K = 1280; N = 2048; k1 = ID; coloff = 0;    ld = 3072; b1 = Wx0; b2 = Wh0; dst = A0; }
  else if (mid == 1) { K = 1280; N = 1024; k1 = ID; coloff = 2048; ld = 3072; b1 = Wx0; b2 = Wh0; dst = B0; }
  else if (mid == 2) { K = 2048; N = 2048; k1 = HD; coloff = 0;    ld = 3072; b1 = Wx1; b2 = Wh1; dst = C1; }
  else if (mid == 3) { K = 2048; N = 1024; k1 = HD; coloff = 2048; ld = 3072; b1 = Wx1; b2 = Wh1; dst = D1; }
  else               { K = 1024; N = 256;  k1 = HD; coloff = 0;    ld = OD;   b1 = Wy;  b2 = Wy;  dst = Y;  }
  int k0 = blockIdx.x << 5, n0 = blockIdx.y << 5;
  if (k0 >= K || n0 >= N) return;
  int tx = threadIdx.x & 31, ty = threadIdx.x >> 5;
#pragma unroll
  for (int i = 0; i < 4; ++i) {
    int kk = (ty << 2) + i, k = k0 + kk;
    int col = coloff + n0 + tx;
    const float* src = (k < k1) ? (b1 + (size_t)k * ld + col)
                                : (b2 + (size_t)(k - k1) * ld + col);
    tile[kk][tx] = f16b(*src);
  }
  __syncthreads();
#pragma unroll
  for (int i = 0; i < 4; ++i) {
    int nn = (ty << 2) + i;
    dst[(size_t)(n0 + nn) * K + k0 + tx] = tile[tx][nn];
  }
}

// ---------------- host launch ----------------

extern "C" void kernel_launch(void* const* d_in, const int* in_sizes, int n_in,
                              void* d_out, int out_size, void* d_ws, size_t ws_size,
                              hipStream_t stream) {
  const float* x    = (const float*)d_in[0];
  const float* h0in = (const float*)d_in[1];
  const float* Wx0  = (const float*)d_in[2];
  const float* Wh0  = (const float*)d_in[3];
  const float* bh0  = (const float*)d_in[4];
  const float* Wx1  = (const float*)d_in[5];
  const float* Wh1  = (const float*)d_in[6];
  const float* bh1  = (const float*)d_in[7];
  const float* Wy   = (const float*)d_in[8];
  const float* by   = (const float*)d_in[9];

  char* ws = (char*)d_ws;
  size_t off = 0;
  auto alloc = [&](size_t bytes) {
    void* p = ws + off;
    off += (bytes + 255) & ~(size_t)255;
    return p;
  };
  u16* WtA0 = (u16*)alloc(2048ull * 1280 * 2);
  u16* WtB0 = (u16*)alloc(1024ull * 1280 * 2);
  u16* WtC1 = (u16*)alloc(2048ull * 2048 * 2);
  u16* WtD1 = (u16*)alloc(1024ull * 2048 * 2);
  u16* WtY  = (u16*)alloc(256ull * 1024 * 2);
  u16* X16  = (u16*)alloc((size_t)MB * SEQ * ID * 2);
  float* h0f32 = (float*)alloc(2ull * MBHD * 4);
  float* h1f32 = (float*)alloc(2ull * MBHD * 4);
  float* z0    = (float*)alloc((size_t)MBHD * 4);
  float* z1    = (float*)alloc((size_t)MBHD * 4);
  u16* h016  = (u16*)alloc(2ull * MBHD * 2);
  u16* h116  = (u16*)alloc(2ull * MBHD * 2);
  u16* rh016 = (u16*)alloc((size_t)MBHD * 2);
  u16* rh116 = (u16*)alloc((size_t)MBHD * 2);

  hipLaunchKernelGGL(convx_k, dim3((MB * SEQ * ID / 8) / 256), dim3(256), 0, stream,
                     x, X16);
  hipLaunchKernelGGL(wtrans_k, dim3(64, 64, 5), dim3(256), 0, stream,
                     Wx0, Wh0, Wx1, Wh1, Wy, WtA0, WtB0, WtC1, WtD1, WtY);
  hipLaunchKernelGGL(inith_k, dim3(65536 / 256), dim3(256), 0, stream,
                     h0in, h0f32, h1f32, h016, h116);

  GruP p;
  p.bh0 = bh0; p.bh1 = bh1; p.by = by;
  p.X16 = X16; p.WtA0 = WtA0; p.WtB0 = WtB0; p.WtC1 = WtC1; p.WtD1 = WtD1; p.WtY = WtY;
  p.h0f32 = h0f32; p.h1f32 = h1f32; p.z0 = z0; p.z1 = z1;
  p.h016 = h016; p.h116 = h116; p.rh016 = rh016; p.rh116 = rh116;
  p.out = (float*)d_out;

  void* args[] = { &p };
  hipLaunchCooperativeKernel((void*)gru_main, dim3(256), dim3(256), args, 0, stream);
}

// Round 4
// 19312.584 us; speedup vs baseline: 2.2698x; 2.2698x over previous
//
#include <hip/hip_runtime.h>

typedef unsigned short u16;
typedef unsigned long long u64;
typedef _Float16 half8 __attribute__((ext_vector_type(8)));
typedef float f32x4 __attribute__((ext_vector_type(4)));

#define SEQ 512
#define MB 32
#define HD 1024
#define ID 256
#define OD 256
#define MBHD (MB * HD)

__device__ __forceinline__ u16 f16b(float v) {
  union { _Float16 h; u16 u; } cv;
  cv.h = (_Float16)v;
  return cv.u;
}
__device__ __forceinline__ u64 pk64(float a, float b) {
  union { float f[2]; u64 u; } c; c.f[0] = a; c.f[1] = b; return c.u;
}
__device__ __forceinline__ float2 upk64(u64 v) {
  union { u64 u; float2 f; } c; c.u = v; return c.f;
}
__device__ __forceinline__ unsigned pk16x2(float a, float b) {
  union { _Float16 h[2]; unsigned u; } c;
  c.h[0] = (_Float16)a; c.h[1] = (_Float16)b; return c.u;
}
// Agent-scope (coherence-point, cross-XCD safe) accesses. All dynamic
// cross-block data goes through these on BOTH sides -> no fence/inv needed.
__device__ __forceinline__ u64 ld_sys64(const void* p) {
  return __hip_atomic_load((const u64*)p, __ATOMIC_RELAXED, __HIP_MEMORY_SCOPE_AGENT);
}
__device__ __forceinline__ void st_sys64(void* p, u64 v) {
  __hip_atomic_store((u64*)p, v, __ATOMIC_RELAXED, __HIP_MEMORY_SCOPE_AGENT);
}
__device__ __forceinline__ void st_sys32(void* p, unsigned v) {
  __hip_atomic_store((unsigned*)p, v, __ATOMIC_RELAXED, __HIP_MEMORY_SCOPE_AGENT);
}

struct GruP {
  const float *bh0, *bh1, *by;
  const u16 *X16, *WtA0, *WtB0, *WtC1, *WtD1, *WtY;
  u16 *h016, *h116;       // fp16 parity-2 [2][MBHD], agent-atomic both sides
  u16 *rh016, *rh116;     // fp16 [MBHD], agent-atomic both sides
  float *h0f32, *h1f32;   // fp32 parity-2 [2][MBHD], agent-atomic both sides
  float *z0, *z1;         // fp32 [MBHD], agent-atomic both sides
  unsigned* bar;
  float* out;
};

// Hierarchical grid barrier: 16 groups of 16 blocks -> root -> epoch flag.
// Release = vmcnt(0): all prior agent-scope atomic stores (executed at the
// coherence point) are complete. No cache fences. Spin is capped so a
// visibility failure degrades to garbage output instead of a hang.
__device__ __forceinline__ void gbar(unsigned* bar, int w, unsigned ep) {
  asm volatile("s_waitcnt vmcnt(0)" ::: "memory");
  __syncthreads();
  if (threadIdx.x == 0) {
    unsigned tgt = ep * 16u + 15u;
    unsigned old = __hip_atomic_fetch_add(&bar[(w >> 4) << 6], 1u,
                                          __ATOMIC_RELAXED, __HIP_MEMORY_SCOPE_AGENT);
    if (old == tgt) {
      unsigned ro = __hip_atomic_fetch_add(&bar[1024], 1u,
                                           __ATOMIC_RELAXED, __HIP_MEMORY_SCOPE_AGENT);
      if (ro == tgt)
        __hip_atomic_store(&bar[1088], ep + 1u,
                           __ATOMIC_RELAXED, __HIP_MEMORY_SCOPE_AGENT);
    }
    for (int spin = 0; spin < (1 << 16); ++spin) {
      if (__hip_atomic_load(&bar[1088], __ATOMIC_RELAXED,
                            __HIP_MEMORY_SCOPE_AGENT) > ep)
        break;
      __builtin_amdgcn_s_sleep(1);
    }
  }
  __syncthreads();
  asm volatile("" ::: "memory");
}

// Stage the X part (chunks [0,32), K1=256) via cached 16B loads (read-only data).
template <int K>
__device__ __forceinline__ void stage_x(u16* sm, const u16* __restrict__ xrow, int tid) {
#pragma unroll
  for (int it = 0; it < 4; ++it) {
    int i = it * 256 + tid;
    int r = i >> 5, c = i & 31;
    int4 v = *(const int4*)(xrow + (size_t)r * (SEQ * ID) + (c << 3));
    *(int4*)(sm + r * K + ((c ^ (r & 7)) << 3)) = v;
  }
}

// Stage one fp16 [32][1024] dynamic source into chunks [C0, C0+128) via
// agent-scope 8B atomic loads. XOR swizzle on 16B chunks matches mm16 reads.
template <int K, int C0>
__device__ __forceinline__ void stage_h(u16* sm, const u16* __restrict__ src, int tid) {
#pragma unroll
  for (int it = 0; it < 32; ++it) {
    int i = it * 256 + tid;
    int r = i >> 8, q = i & 255;
    u64 v = ld_sys64(src + (size_t)r * HD + (q << 2));
    int c16 = C0 + (q >> 1), hs = q & 1;
    *(u64*)(sm + r * K + ((c16 ^ (r & 7)) << 3) + (hs << 2)) = v;
  }
}

// One wave: partial [32 x 16] over its K-quarter. Weights [N][K] cached (L2).
template <int K>
__device__ __forceinline__ void mm16(const u16* sm, const u16* __restrict__ Wt,
                                     int n0, int wave, int lane, f32x4& a0, f32x4& a1) {
  constexpr int NST = K >> 7;
  int b = lane >> 4, rr = lane & 15, sw = rr & 7;
  const u16* wrow = Wt + (size_t)(n0 + rr) * K + (b << 3);
  const u16* ar0 = sm + rr * K;
  const u16* ar1 = sm + (16 + rr) * K;
  int kbeg = wave * (K >> 2);
#pragma unroll
  for (int s = 0; s < NST; ++s) {
    int k0 = kbeg + (s << 5);
    int ci = (k0 >> 3) + b;
    half8 A0 = *(const half8*)(ar0 + ((ci ^ sw) << 3));
    half8 A1 = *(const half8*)(ar1 + ((ci ^ sw) << 3));
    half8 Bf = *(const half8*)(wrow + k0);
    a0 = __builtin_amdgcn_mfma_f32_16x16x32_f16(A0, Bf, a0, 0, 0, 0);
    a1 = __builtin_amdgcn_mfma_f32_16x16x32_f16(A1, Bf, a1, 0, 0, 0);
  }
}

__global__ void __launch_bounds__(256, 1) gru_main(GruP p) {
  __shared__ __align__(16) u16 sm[MB * 2048];  // 128 KB staged input
  __shared__ float psum[4][MB][16];            // 8 KB cross-wave partials
  const int w = blockIdx.x, tid = threadIdx.x;
  const int wave = tid >> 6, lane = tid & 63;
  const int m = tid >> 3, jc = (tid & 7) << 1;

  for (int t = 0; t <= SEQ + 1; ++t) {
    // ============ tick ALPHA: z,r gates (L0 step t | L1 step t-1) ============
    if (w < 128) {
      if (t < SEQ) {
        int n0 = w << 4;
        stage_x<1280>(sm, p.X16 + (size_t)t * ID, tid);
        stage_h<1280, 32>(sm, p.h016 + (size_t)((t + 1) & 1) * MBHD, tid);
        __syncthreads();
        f32x4 a0 = {0.f, 0.f, 0.f, 0.f}, a1 = {0.f, 0.f, 0.f, 0.f};
        mm16<1280>(sm, p.WtA0, n0, wave, lane, a0, a1);
        int cc = lane & 15, rb = (lane >> 4) << 2;
#pragma unroll
        for (int i = 0; i < 4; ++i) {
          psum[wave][rb + i][cc] = a0[i];
          psum[wave][16 + rb + i][cc] = a1[i];
        }
        __syncthreads();
        float2 s0 = *(const float2*)&psum[0][m][jc];
        float2 s1v = *(const float2*)&psum[1][m][jc];
        float2 s2v = *(const float2*)&psum[2][m][jc];
        float2 s3v = *(const float2*)&psum[3][m][jc];
        int j0 = n0 + jc;
        float v0 = s0.x + s1v.x + s2v.x + s3v.x + p.bh0[j0];
        float v1 = s0.y + s1v.y + s2v.y + s3v.y + p.bh0[j0 + 1];
        v0 = 1.f / (1.f + __expf(-v0));
        v1 = 1.f / (1.f + __expf(-v1));
        if (j0 < HD) {
          st_sys64(&p.z0[m * HD + j0], pk64(v0, v1));
        } else {
          int jr = j0 - HD;
          const float* hprev = p.h0f32 + (size_t)((t + 1) & 1) * MBHD;
          float2 hp = upk64(ld_sys64(&hprev[m * HD + jr]));
          st_sys32(p.rh016 + m * HD + jr, pk16x2(v0 * hp.x, v1 * hp.y));
        }
      }
    } else {
      if (t >= 1 && t <= SEQ) {
        int n0 = (w - 128) << 4;
        stage_h<2048, 0>(sm, p.h016 + (size_t)((t - 1) & 1) * MBHD, tid);
        stage_h<2048, 128>(sm, p.h116 + (size_t)(t & 1) * MBHD, tid);
        __syncthreads();
        f32x4 a0 = {0.f, 0.f, 0.f, 0.f}, a1 = {0.f, 0.f, 0.f, 0.f};
        mm16<2048>(sm, p.WtC1, n0, wave, lane, a0, a1);
        int cc = lane & 15, rb = (lane >> 4) << 2;
#pragma unroll
        for (int i = 0; i < 4; ++i) {
          psum[wave][rb + i][cc] = a0[i];
          psum[wave][16 + rb + i][cc] = a1[i];
        }
        __syncthreads();
        float2 s0 = *(const float2*)&psum[0][m][jc];
        float2 s1v = *(const float2*)&psum[1][m][jc];
        float2 s2v = *(const float2*)&psum[2][m][jc];
        float2 s3v = *(const float2*)&psum[3][m][jc];
        int j0 = n0 + jc;
        float v0 = s0.x + s1v.x + s2v.x + s3v.x + p.bh1[j0];
        float v1 = s0.y + s1v.y + s2v.y + s3v.y + p.bh1[j0 + 1];
        v0 = 1.f / (1.f + __expf(-v0));
        v1 = 1.f / (1.f + __expf(-v1));
        if (j0 < HD) {
          st_sys64(&p.z1[m * HD + j0], pk64(v0, v1));
        } else {
          int jr = j0 - HD;
          const float* hprev = p.h1f32 + (size_t)(t & 1) * MBHD;
          float2 hp = upk64(ld_sys64(&hprev[m * HD + jr]));
          st_sys32(p.rh116 + m * HD + jr, pk16x2(v0 * hp.x, v1 * hp.y));
        }
      }
    }
    gbar(p.bar, w, 2u * t);
    // ============ tick BETA: g + h update (L0 t | L1 t-1), y(t-2) ============
    if (w < 64) {
      if (t < SEQ) {
        int n0 = w << 4;
        stage_x<1280>(sm, p.X16 + (size_t)t * ID, tid);
        stage_h<1280, 32>(sm, p.rh016, tid);
        __syncthreads();
        f32x4 a0 = {0.f, 0.f, 0.f, 0.f}, a1 = {0.f, 0.f, 0.f, 0.f};
        mm16<1280>(sm, p.WtB0, n0, wave, lane, a0, a1);
        int cc = lane & 15, rb = (lane >> 4) << 2;
#pragma unroll
        for (int i = 0; i < 4; ++i) {
          psum[wave][rb + i][cc] = a0[i];
          psum[wave][16 + rb + i][cc] = a1[i];
        }
        __syncthreads();
        float2 s0 = *(const float2*)&psum[0][m][jc];
        float2 s1v = *(const float2*)&psum[1][m][jc];
        float2 s2v = *(const float2*)&psum[2][m][jc];
        float2 s3v = *(const float2*)&psum[3][m][jc];
        int j0 = n0 + jc;
        float v0 = s0.x + s1v.x + s2v.x + s3v.x + p.bh0[2 * HD + j0];
        float v1 = s0.y + s1v.y + s2v.y + s3v.y + p.bh0[2 * HD + j0 + 1];
        float g0 = tanhf(v0), g1 = tanhf(v1);
        const float* hprev = p.h0f32 + (size_t)((t + 1) & 1) * MBHD;
        float2 hp = upk64(ld_sys64(&hprev[m * HD + j0]));
        float2 zz = upk64(ld_sys64(&p.z0[m * HD + j0]));
        float hn0 = zz.x * hp.x + (1.f - zz.x) * g0;
        float hn1 = zz.y * hp.y + (1.f - zz.y) * g1;
        st_sys64(p.h0f32 + (size_t)(t & 1) * MBHD + m * HD + j0, pk64(hn0, hn1));
        st_sys32(p.h016 + (size_t)(t & 1) * MBHD + m * HD + j0, pk16x2(hn0, hn1));
      }
    } else if (w < 80) {
      if (t >= 2) {
        int n0 = (w - 64) << 4;
        stage_h<1024, 0>(sm, p.h116 + (size_t)(t & 1) * MBHD, tid);
        __syncthreads();
        f32x4 a0 = {0.f, 0.f, 0.f, 0.f}, a1 = {0.f, 0.f, 0.f, 0.f};
        mm16<1024>(sm, p.WtY, n0, wave, lane, a0, a1);
        int cc = lane & 15, rb = (lane >> 4) << 2;
#pragma unroll
        for (int i = 0; i < 4; ++i) {
          psum[wave][rb + i][cc] = a0[i];
          psum[wave][16 + rb + i][cc] = a1[i];
        }
        __syncthreads();
        float2 s0 = *(const float2*)&psum[0][m][jc];
        float2 s1v = *(const float2*)&psum[1][m][jc];
        float2 s2v = *(const float2*)&psum[2][m][jc];
        float2 s3v = *(const float2*)&psum[3][m][jc];
        int j0 = n0 + jc;
        float v0 = s0.x + s1v.x + s2v.x + s3v.x + p.by[j0];
        float v1 = s0.y + s1v.y + s2v.y + s3v.y + p.by[j0 + 1];
        *(float2*)&p.out[((size_t)m * SEQ + (t - 2)) * OD + j0] = make_float2(v0, v1);
      }
    } else if (w >= 128 && w < 192) {
      if (t >= 1 && t <= SEQ) {
        int n0 = (w - 128) << 4;
        stage_h<2048, 0>(sm, p.h016 + (size_t)((t - 1) & 1) * MBHD, tid);
        stage_h<2048, 128>(sm, p.rh116, tid);
        __syncthreads();
        f32x4 a0 = {0.f, 0.f, 0.f, 0.f}, a1 = {0.f, 0.f, 0.f, 0.f};
        mm16<2048>(sm, p.WtD1, n0, wave, lane, a0, a1);
        int cc = lane & 15, rb = (lane >> 4) << 2;
#pragma unroll
        for (int i = 0; i < 4; ++i) {
          psum[wave][rb + i][cc] = a0[i];
          psum[wave][16 + rb + i][cc] = a1[i];
        }
        __syncthreads();
        float2 s0 = *(const float2*)&psum[0][m][jc];
        float2 s1v = *(const float2*)&psum[1][m][jc];
        float2 s2v = *(const float2*)&psum[2][m][jc];
        float2 s3v = *(const float2*)&psum[3][m][jc];
        int j0 = n0 + jc;
        float v0 = s0.x + s1v.x + s2v.x + s3v.x + p.bh1[2 * HD + j0];
        float v1 = s0.y + s1v.y + s2v.y + s3v.y + p.bh1[2 * HD + j0 + 1];
        float g0 = tanhf(v0), g1 = tanhf(v1);
        const float* hprev = p.h1f32 + (size_t)(t & 1) * MBHD;
        float2 hp = upk64(ld_sys64(&hprev[m * HD + j0]));
        float2 zz = upk64(ld_sys64(&p.z1[m * HD + j0]));
        float hn0 = zz.x * hp.x + (1.f - zz.x) * g0;
        float hn1 = zz.y * hp.y + (1.f - zz.y) * g1;
        st_sys64(p.h1f32 + (size_t)((t - 1) & 1) * MBHD + m * HD + j0, pk64(hn0, hn1));
        st_sys32(p.h116 + (size_t)((t - 1) & 1) * MBHD + m * HD + j0,
                 pk16x2(hn0, hn1));
      }
    }
    gbar(p.bar, w, 2u * t + 1u);
  }
  // Epilogue: final hidden states (both in parity buffer 1 after step 511).
  if (w < MB) {
    const float* h0f = p.h0f32 + MBHD;
    const float* h1f = p.h1f32 + MBHD;
#pragma unroll
    for (int it = 0; it < 4; ++it) {
      int i2 = (it * 256 + tid) * 2;  // 0..2046 step 2 over 2*HD
      float2 v = (i2 < HD) ? upk64(ld_sys64(&h0f[w * HD + i2]))
                           : upk64(ld_sys64(&h1f[w * HD + (i2 - HD)]));
      *(float2*)&p.out[(size_t)MB * SEQ * OD + (size_t)w * 2 * HD + i2] = v;
    }
  }
}

// ---------------- prologue kernels ----------------

__global__ void convx_k(const float* __restrict__ x, u16* __restrict__ X16) {
  size_t i = (size_t)blockIdx.x * 256 + threadIdx.x;
  const float4* s = (const float4*)x + i * 2;
  float4 a = s[0], b = s[1];
  u16 o[8];
  o[0] = f16b(a.x); o[1] = f16b(a.y); o[2] = f16b(a.z); o[3] = f16b(a.w);
  o[4] = f16b(b.x); o[5] = f16b(b.y); o[6] = f16b(b.z); o[7] = f16b(b.w);
  *(int4*)(X16 + i * 8) = *(const int4*)o;
}

__global__ void inith_k(const float* __restrict__ h0in,
                        float* h0f32, float* h1f32, u16* h016, u16* h116) {
  int idx = blockIdx.x * 256 + threadIdx.x;  // [b][l][h], 65536
  float v = h0in[idx];
  int b = idx >> 11, rem = idx & 2047;
  int l = rem >> 10, h = rem & 1023;
  int o = MBHD + b * HD + h;                 // parity buffer 1
  if (l == 0) { h0f32[o] = v; h016[o] = f16b(v); }
  else        { h1f32[o] = v; h116[o] = f16b(v); }
}

// Build [N][K] fp16 transposed weight blocks (K = concat Wx rows then Wh rows).
__global__ void wtrans_k(const float* __restrict__ Wx0, const float* __restrict__ Wh0,
                         const float* __restrict__ Wx1, const float* __restrict__ Wh1,
                         const float* __restrict__ Wy,
                         u16* A0, u16* B0, u16* C1, u16* D1, u16* Y) {
  __shared__ u16 tile[32][34];
  int mid = blockIdx.z;
  int K, N, k1, coloff, ld; const float *b1, *b2; u16* dst;
  if (mid == 0)      { K = 1280; N = 2048; k1 = ID; coloff = 0;    ld = 3072; b1 = Wx0; b2 = Wh0; dst = A0; }
  else if (mid == 1) { K = 1280; N = 1024; k1 = ID; coloff = 2048; ld = 3072; b1 = Wx0; b2 = Wh0; dst = B0; }
  else if (mid == 2) { K = 2048; N = 2048; k1 = HD; coloff = 0;    ld = 3072; b1 = Wx1; b2 = Wh1; dst = C1; }
  else if (mid == 3) { K = 2048; N = 1024; k1 = HD; coloff = 2048; ld = 3072; b1 = Wx1; b2 = Wh1; dst = D1; }
  else               { K = 1024; N = 256;  k1 = HD; coloff = 0;    ld = OD;   b1 = Wy;  b2 = Wy;  dst = Y;  }
  int k0 = blockIdx.x << 5, n0 = blockIdx.y << 5;
  if (k0 >= K || n0 >= N) return;
  int tx = threadIdx.x & 31, ty = threadIdx.x >> 5;
#pragma unroll
  for (int i = 0; i < 4; ++i) {
    int kk = (ty << 2) + i, k = k0 + kk;
    int col = coloff + n0 + tx;
    const float* src = (k < k1) ? (b1 + (size_t)k * ld + col)
                                : (b2 + (size_t)(k - k1) * ld + col);
    tile[kk][tx] = f16b(*src);
  }
  __syncthreads();
#pragma unroll
  for (int i = 0; i < 4; ++i) {
    int nn = (ty << 2) + i;
    dst[(size_t)(n0 + nn) * K + k0 + tx] = tile[tx][nn];
  }
}

// ---------------- host launch ----------------

extern "C" void kernel_launch(void* const* d_in, const int* in_sizes, int n_in,
                              void* d_out, int out_size, void* d_ws, size_t ws_size,
                              hipStream_t stream) {
  const float* x    = (const float*)d_in[0];
  const float* h0in = (const float*)d_in[1];
  const float* Wx0  = (const float*)d_in[2];
  const float* Wh0  = (const float*)d_in[3];
  const float* bh0  = (const float*)d_in[4];
  const float* Wx1  = (const float*)d_in[5];
  const float* Wh1  = (const float*)d_in[6];
  const float* bh1  = (const float*)d_in[7];
  const float* Wy   = (const float*)d_in[8];
  const float* by   = (const float*)d_in[9];

  char* ws = (char*)d_ws;
  size_t off = 0;
  auto alloc = [&](size_t bytes) {
    void* pp = ws + off;
    off += (bytes + 255) & ~(size_t)255;
    return pp;
  };
  u16* WtA0 = (u16*)alloc(2048ull * 1280 * 2);
  u16* WtB0 = (u16*)alloc(1024ull * 1280 * 2);
  u16* WtC1 = (u16*)alloc(2048ull * 2048 * 2);
  u16* WtD1 = (u16*)alloc(1024ull * 2048 * 2);
  u16* WtY  = (u16*)alloc(256ull * 1024 * 2);
  u16* X16  = (u16*)alloc((size_t)MB * SEQ * ID * 2);
  u16* h016  = (u16*)alloc(2ull * MBHD * 2);
  u16* h116  = (u16*)alloc(2ull * MBHD * 2);
  u16* rh016 = (u16*)alloc((size_t)MBHD * 2);
  u16* rh116 = (u16*)alloc((size_t)MBHD * 2);
  float* h0f32 = (float*)alloc(2ull * MBHD * 4);
  float* h1f32 = (float*)alloc(2ull * MBHD * 4);
  float* z0    = (float*)alloc((size_t)MBHD * 4);
  float* z1    = (float*)alloc((size_t)MBHD * 4);
  unsigned* bar = (unsigned*)alloc(8192);

  hipMemsetAsync(bar, 0, 8192, stream);
  hipLaunchKernelGGL(convx_k, dim3((MB * SEQ * ID / 8) / 256), dim3(256), 0, stream,
                     x, X16);
  hipLaunchKernelGGL(wtrans_k, dim3(64, 64, 5), dim3(256), 0, stream,
                     Wx0, Wh0, Wx1, Wh1, Wy, WtA0, WtB0, WtC1, WtD1, WtY);
  hipLaunchKernelGGL(inith_k, dim3(65536 / 256), dim3(256), 0, stream,
                     h0in, h0f32, h1f32, h016, h116);

  GruP p;
  p.bh0 = bh0; p.bh1 = bh1; p.by = by;
  p.X16 = X16; p.WtA0 = WtA0; p.WtB0 = WtB0; p.WtC1 = WtC1; p.WtD1 = WtD1; p.WtY = WtY;
  p.h016 = h016; p.h116 = h116; p.rh016 = rh016; p.rh116 = rh116;
  p.h0f32 = h0f32; p.h1f32 = h1f32; p.z0 = z0; p.z1 = z1;
  p.bar = bar;
  p.out = (float*)d_out;

  // Plain launch: the barrier uses agent-scope atomics only (no cg API), and
  // co-residency is structural (136 KB LDS -> 1 block/CU, 256 blocks = 256 CUs;
  // round-1's successful cooperative launch proved this co-residency on HW).
  hipLaunchKernelGGL(gru_main, dim3(256), dim3(256), 0, stream, p);
}

// Round 5
// 7634.225 us; speedup vs baseline: 5.7420x; 2.5297x over previous
//
#include <hip/hip_runtime.h>

typedef unsigned short u16;
typedef unsigned long long u64;
typedef _Float16 half8 __attribute__((ext_vector_type(8)));
typedef float f32x4 __attribute__((ext_vector_type(4)));
typedef int i32x4 __attribute__((ext_vector_type(4)));

#define SEQ 512
#define MB 32
#define HD 1024
#define ID 256
#define OD 256
#define MBHD (MB * HD)

__device__ __forceinline__ u16 f16b(float v) {
  union { _Float16 h; u16 u; } cv;
  cv.h = (_Float16)v;
  return cv.u;
}
__device__ __forceinline__ u64 pk64(float a, float b) {
  union { float f[2]; u64 u; } c; c.f[0] = a; c.f[1] = b; return c.u;
}
__device__ __forceinline__ float2 upk64(u64 v) {
  union { u64 u; float2 f; } c; c.u = v; return c.f;
}
__device__ __forceinline__ unsigned pk16x2(float a, float b) {
  union { _Float16 h[2]; unsigned u; } c;
  c.h[0] = (_Float16)a; c.h[1] = (_Float16)b; return c.u;
}

// ---- coherent (MALL-point, cross-XCD safe) NON-ATOMIC ops: sc0 sc1 =
// bypass L1+L2, read/write at the coherence point (same encoding LLVM emits
// for system-scope accesses). Unlike atomics these coalesce across lanes.
__device__ __forceinline__ void cst4(void* p, unsigned v) {
  asm volatile("global_store_dword %0, %1, off sc0 sc1" :: "v"(p), "v"(v) : "memory");
}
__device__ __forceinline__ void cst8(void* p, u64 v) {
  asm volatile("global_store_dwordx2 %0, %1, off sc0 sc1" :: "v"(p), "v"(v) : "memory");
}
__device__ __forceinline__ u64 cld8(const void* p) {
  u64 v;
  asm volatile("global_load_dwordx2 %0, %1, off sc0 sc1\n\ts_waitcnt vmcnt(0)"
               : "=&v"(v) : "v"(p) : "memory");
  return v;
}
__device__ __forceinline__ void cld8x2(const void* p0, const void* p1, u64& a, u64& b) {
  asm volatile("global_load_dwordx2 %0, %2, off sc0 sc1\n\t"
               "global_load_dwordx2 %1, %3, off sc0 sc1\n\t"
               "s_waitcnt vmcnt(0)"
               : "=&v"(a), "=&v"(b) : "v"(p0), "v"(p1) : "memory");
}

struct GruP {
  const float *bh0, *bh1, *by;
  const u16 *X16, *WtA0, *WtB0, *WtC1, *WtD1, *WtY;
  u16 *h016, *h116;       // fp16 parity-2 [2][MBHD], coherent both sides
  u16 *rh016, *rh116;     // fp16 [MBHD], coherent both sides
  float *h0f32, *h1f32;   // fp32 parity-2 [2][MBHD], coherent both sides
  float *z0, *z1;         // fp32 [MBHD], coherent both sides
  unsigned* bar;
  float* out;
};

// Hierarchical grid barrier (round-4 proven): 16 groups -> root -> epoch flag.
// Release = vmcnt(0): all prior coherent stores complete at the MALL.
__device__ __forceinline__ void gbar(unsigned* bar, int w, unsigned ep) {
  asm volatile("s_waitcnt vmcnt(0)" ::: "memory");
  __syncthreads();
  if (threadIdx.x == 0) {
    unsigned tgt = ep * 16u + 15u;
    unsigned old = __hip_atomic_fetch_add(&bar[(w >> 4) << 6], 1u,
                                          __ATOMIC_RELAXED, __HIP_MEMORY_SCOPE_AGENT);
    if (old == tgt) {
      unsigned ro = __hip_atomic_fetch_add(&bar[1024], 1u,
                                           __ATOMIC_RELAXED, __HIP_MEMORY_SCOPE_AGENT);
      if (ro == tgt)
        __hip_atomic_store(&bar[1088], ep + 1u,
                           __ATOMIC_RELAXED, __HIP_MEMORY_SCOPE_AGENT);
    }
    for (int spin = 0; spin < (1 << 16); ++spin) {
      if (__hip_atomic_load(&bar[1088], __ATOMIC_RELAXED,
                            __HIP_MEMORY_SCOPE_AGENT) > ep)
        break;
      __builtin_amdgcn_s_sleep(1);
    }
  }
  __syncthreads();
  asm volatile("" ::: "memory");
}

// Stage the X part (chunks [0,32), K1=256) via cached 16B loads (read-only data).
template <int K>
__device__ __forceinline__ void stage_x(u16* sm, const u16* __restrict__ xrow, int tid) {
#pragma unroll
  for (int it = 0; it < 4; ++it) {
    int i = it * 256 + tid;
    int r = i >> 5, c = i & 31;
    i32x4 v = *(const i32x4*)(xrow + (size_t)r * (SEQ * ID) + (c << 3));
    *(i32x4*)(sm + r * K + ((c ^ (r & 7)) << 3)) = v;
  }
}

// Stage one fp16 [32][1024] dynamic source into chunks [C0, C0+128) via
// coherent COALESCED 16B loads, batched 8-per-wait (pipelined latency).
// Consecutive lanes -> consecutive 16B -> perfect wave coalescing.
template <int K, int C0>
__device__ __forceinline__ void stage_h(u16* sm, const u16* __restrict__ src, int tid) {
#pragma unroll
  for (int bt = 0; bt < 2; ++bt) {
    const u16* pa[8];
    int rr[8], qq[8];
#pragma unroll
    for (int u = 0; u < 8; ++u) {
      int i = (bt * 8 + u) * 256 + tid;
      rr[u] = i >> 7;
      qq[u] = i & 127;
      pa[u] = src + rr[u] * HD + (qq[u] << 3);
    }
    i32x4 v0, v1, v2, v3, v4, v5, v6, v7;
    asm volatile(
        "global_load_dwordx4 %0, %8, off sc0 sc1\n\t"
        "global_load_dwordx4 %1, %9, off sc0 sc1\n\t"
        "global_load_dwordx4 %2, %10, off sc0 sc1\n\t"
        "global_load_dwordx4 %3, %11, off sc0 sc1\n\t"
        "global_load_dwordx4 %4, %12, off sc0 sc1\n\t"
        "global_load_dwordx4 %5, %13, off sc0 sc1\n\t"
        "global_load_dwordx4 %6, %14, off sc0 sc1\n\t"
        "global_load_dwordx4 %7, %15, off sc0 sc1\n\t"
        "s_waitcnt vmcnt(0)"
        : "=&v"(v0), "=&v"(v1), "=&v"(v2), "=&v"(v3),
          "=&v"(v4), "=&v"(v5), "=&v"(v6), "=&v"(v7)
        : "v"(pa[0]), "v"(pa[1]), "v"(pa[2]), "v"(pa[3]),
          "v"(pa[4]), "v"(pa[5]), "v"(pa[6]), "v"(pa[7])
        : "memory");
    *(i32x4*)(sm + rr[0] * K + (((C0 + qq[0]) ^ (rr[0] & 7)) << 3)) = v0;
    *(i32x4*)(sm + rr[1] * K + (((C0 + qq[1]) ^ (rr[1] & 7)) << 3)) = v1;
    *(i32x4*)(sm + rr[2] * K + (((C0 + qq[2]) ^ (rr[2] & 7)) << 3)) = v2;
    *(i32x4*)(sm + rr[3] * K + (((C0 + qq[3]) ^ (rr[3] & 7)) << 3)) = v3;
    *(i32x4*)(sm + rr[4] * K + (((C0 + qq[4]) ^ (rr[4] & 7)) << 3)) = v4;
    *(i32x4*)(sm + rr[5] * K + (((C0 + qq[5]) ^ (rr[5] & 7)) << 3)) = v5;
    *(i32x4*)(sm + rr[6] * K + (((C0 + qq[6]) ^ (rr[6] & 7)) << 3)) = v6;
    *(i32x4*)(sm + rr[7] * K + (((C0 + qq[7]) ^ (rr[7] & 7)) << 3)) = v7;
  }
}

// One wave: partial [32 x 16] over its K-quarter. Weights [N][K] cached (L2).
template <int K>
__device__ __forceinline__ void mm16(const u16* sm, const u16* __restrict__ Wt,
                                     int n0, int wave, int lane, f32x4& a0, f32x4& a1) {
  constexpr int NST = K >> 7;
  int b = lane >> 4, rr = lane & 15, sw = rr & 7;
  const u16* wrow = Wt + (size_t)(n0 + rr) * K + (b << 3);
  const u16* ar0 = sm + rr * K;
  const u16* ar1 = sm + (16 + rr) * K;
  int kbeg = wave * (K >> 2);
#pragma unroll
  for (int s = 0; s < NST; ++s) {
    int k0 = kbeg + (s << 5);
    int ci = (k0 >> 3) + b;
    half8 A0 = *(const half8*)(ar0 + ((ci ^ sw) << 3));
    half8 A1 = *(const half8*)(ar1 + ((ci ^ sw) << 3));
    half8 Bf = *(const half8*)(wrow + k0);
    a0 = __builtin_amdgcn_mfma_f32_16x16x32_f16(A0, Bf, a0, 0, 0, 0);
    a1 = __builtin_amdgcn_mfma_f32_16x16x32_f16(A1, Bf, a1, 0, 0, 0);
  }
}

__global__ void __launch_bounds__(256, 1) gru_main(GruP p) {
  __shared__ __align__(16) u16 sm[MB * 2048];  // 128 KB staged input
  __shared__ float psum[4][MB][16];            // 8 KB cross-wave partials
  const int w = blockIdx.x, tid = threadIdx.x;
  const int wave = tid >> 6, lane = tid & 63;
  const int m = tid >> 3, jc = (tid & 7) << 1;

  for (int t = 0; t <= SEQ + 1; ++t) {
    // ============ tick ALPHA: z,r gates (L0 step t | L1 step t-1) ============
    if (w < 128) {
      if (t < SEQ) {
        int n0 = w << 4;
        stage_x<1280>(sm, p.X16 + (size_t)t * ID, tid);
        stage_h<1280, 32>(sm, p.h016 + (size_t)((t + 1) & 1) * MBHD, tid);
        __syncthreads();
        f32x4 a0 = {0.f, 0.f, 0.f, 0.f}, a1 = {0.f, 0.f, 0.f, 0.f};
        mm16<1280>(sm, p.WtA0, n0, wave, lane, a0, a1);
        int cc = lane & 15, rb = (lane >> 4) << 2;
#pragma unroll
        for (int i = 0; i < 4; ++i) {
          psum[wave][rb + i][cc] = a0[i];
          psum[wave][16 + rb + i][cc] = a1[i];
        }
        __syncthreads();
        float2 s0 = *(const float2*)&psum[0][m][jc];
        float2 s1v = *(const float2*)&psum[1][m][jc];
        float2 s2v = *(const float2*)&psum[2][m][jc];
        float2 s3v = *(const float2*)&psum[3][m][jc];
        int j0 = n0 + jc;
        float v0 = s0.x + s1v.x + s2v.x + s3v.x + p.bh0[j0];
        float v1 = s0.y + s1v.y + s2v.y + s3v.y + p.bh0[j0 + 1];
        v0 = 1.f / (1.f + __expf(-v0));
        v1 = 1.f / (1.f + __expf(-v1));
        if (j0 < HD) {
          cst8(&p.z0[m * HD + j0], pk64(v0, v1));
        } else {
          int jr = j0 - HD;
          const float* hprev = p.h0f32 + (size_t)((t + 1) & 1) * MBHD;
          float2 hp = upk64(cld8(&hprev[m * HD + jr]));
          cst4(p.rh016 + m * HD + jr, pk16x2(v0 * hp.x, v1 * hp.y));
        }
      }
    } else {
      if (t >= 1 && t <= SEQ) {
        int n0 = (w - 128) << 4;
        stage_h<2048, 0>(sm, p.h016 + (size_t)((t - 1) & 1) * MBHD, tid);
        stage_h<2048, 128>(sm, p.h116 + (size_t)(t & 1) * MBHD, tid);
        __syncthreads();
        f32x4 a0 = {0.f, 0.f, 0.f, 0.f}, a1 = {0.f, 0.f, 0.f, 0.f};
        mm16<2048>(sm, p.WtC1, n0, wave, lane, a0, a1);
        int cc = lane & 15, rb = (lane >> 4) << 2;
#pragma unroll
        for (int i = 0; i < 4; ++i) {
          psum[wave][rb + i][cc] = a0[i];
          psum[wave][16 + rb + i][cc] = a1[i];
        }
        __syncthreads();
        float2 s0 = *(const float2*)&psum[0][m][jc];
        float2 s1v = *(const float2*)&psum[1][m][jc];
        float2 s2v = *(const float2*)&psum[2][m][jc];
        float2 s3v = *(const float2*)&psum[3][m][jc];
        int j0 = n0 + jc;
        float v0 = s0.x + s1v.x + s2v.x + s3v.x + p.bh1[j0];
        float v1 = s0.y + s1v.y + s2v.y + s3v.y + p.bh1[j0 + 1];
        v0 = 1.f / (1.f + __expf(-v0));
        v1 = 1.f / (1.f + __expf(-v1));
        if (j0 < HD) {
          cst8(&p.z1[m * HD + j0], pk64(v0, v1));
        } else {
          int jr = j0 - HD;
          const float* hprev = p.h1f32 + (size_t)(t & 1) * MBHD;
          float2 hp = upk64(cld8(&hprev[m * HD + jr]));
          cst4(p.rh116 + m * HD + jr, pk16x2(v0 * hp.x, v1 * hp.y));
        }
      }
    }
    gbar(p.bar, w, 2u * t);
    // ============ tick BETA: g + h update (L0 t | L1 t-1), y(t-2) ============
    if (w < 64) {
      if (t < SEQ) {
        int n0 = w << 4;
        stage_x<1280>(sm, p.X16 + (size_t)t * ID, tid);
        stage_h<1280, 32>(sm, p.rh016, tid);
        __syncthreads();
        f32x4 a0 = {0.f, 0.f, 0.f, 0.f}, a1 = {0.f, 0.f, 0.f, 0.f};
        mm16<1280>(sm, p.WtB0, n0, wave, lane, a0, a1);
        int cc = lane & 15, rb = (lane >> 4) << 2;
#pragma unroll
        for (int i = 0; i < 4; ++i) {
          psum[wave][rb + i][cc] = a0[i];
          psum[wave][16 + rb + i][cc] = a1[i];
        }
        __syncthreads();
        float2 s0 = *(const float2*)&psum[0][m][jc];
        float2 s1v = *(const float2*)&psum[1][m][jc];
        float2 s2v = *(const float2*)&psum[2][m][jc];
        float2 s3v = *(const float2*)&psum[3][m][jc];
        int j0 = n0 + jc;
        float v0 = s0.x + s1v.x + s2v.x + s3v.x + p.bh0[2 * HD + j0];
        float v1 = s0.y + s1v.y + s2v.y + s3v.y + p.bh0[2 * HD + j0 + 1];
        float g0 = tanhf(v0), g1 = tanhf(v1);
        const float* hprev = p.h0f32 + (size_t)((t + 1) & 1) * MBHD;
        u64 hpv, zzv;
        cld8x2(&hprev[m * HD + j0], &p.z0[m * HD + j0], hpv, zzv);
        float2 hp = upk64(hpv);
        float2 zz = upk64(zzv);
        float hn0 = zz.x * hp.x + (1.f - zz.x) * g0;
        float hn1 = zz.y * hp.y + (1.f - zz.y) * g1;
        cst8(p.h0f32 + (size_t)(t & 1) * MBHD + m * HD + j0, pk64(hn0, hn1));
        cst4(p.h016 + (size_t)(t & 1) * MBHD + m * HD + j0, pk16x2(hn0, hn1));
      }
    } else if (w < 80) {
      if (t >= 2) {
        int n0 = (w - 64) << 4;
        stage_h<1024, 0>(sm, p.h116 + (size_t)(t & 1) * MBHD, tid);
        __syncthreads();
        f32x4 a0 = {0.f, 0.f, 0.f, 0.f}, a1 = {0.f, 0.f, 0.f, 0.f};
        mm16<1024>(sm, p.WtY, n0, wave, lane, a0, a1);
        int cc = lane & 15, rb = (lane >> 4) << 2;
#pragma unroll
        for (int i = 0; i < 4; ++i) {
          psum[wave][rb + i][cc] = a0[i];
          psum[wave][16 + rb + i][cc] = a1[i];
        }
        __syncthreads();
        float2 s0 = *(const float2*)&psum[0][m][jc];
        float2 s1v = *(const float2*)&psum[1][m][jc];
        float2 s2v = *(const float2*)&psum[2][m][jc];
        float2 s3v = *(const float2*)&psum[3][m][jc];
        int j0 = n0 + jc;
        float v0 = s0.x + s1v.x + s2v.x + s3v.x + p.by[j0];
        float v1 = s0.y + s1v.y + s2v.y + s3v.y + p.by[j0 + 1];
        *(float2*)&p.out[((size_t)m * SEQ + (t - 2)) * OD + j0] = make_float2(v0, v1);
      }
    } else if (w >= 128 && w < 192) {
      if (t >= 1 && t <= SEQ) {
        int n0 = (w - 128) << 4;
        stage_h<2048, 0>(sm, p.h016 + (size_t)((t - 1) & 1) * MBHD, tid);
        stage_h<2048, 128>(sm, p.rh116, tid);
        __syncthreads();
        f32x4 a0 = {0.f, 0.f, 0.f, 0.f}, a1 = {0.f, 0.f, 0.f, 0.f};
        mm16<2048>(sm, p.WtD1, n0, wave, lane, a0, a1);
        int cc = lane & 15, rb = (lane >> 4) << 2;
#pragma unroll
        for (int i = 0; i < 4; ++i) {
          psum[wave][rb + i][cc] = a0[i];
          psum[wave][16 + rb + i][cc] = a1[i];
        }
        __syncthreads();
        float2 s0 = *(const float2*)&psum[0][m][jc];
        float2 s1v = *(const float2*)&psum[1][m][jc];
        float2 s2v = *(const float2*)&psum[2][m][jc];
        float2 s3v = *(const float2*)&psum[3][m][jc];
        int j0 = n0 + jc;
        float v0 = s0.x + s1v.x + s2v.x + s3v.x + p.bh1[2 * HD + j0];
        float v1 = s0.y + s1v.y + s2v.y + s3v.y + p.bh1[2 * HD + j0 + 1];
        float g0 = tanhf(v0), g1 = tanhf(v1);
        const float* hprev = p.h1f32 + (size_t)(t & 1) * MBHD;
        u64 hpv, zzv;
        cld8x2(&hprev[m * HD + j0], &p.z1[m * HD + j0], hpv, zzv);
        float2 hp = upk64(hpv);
        float2 zz = upk64(zzv);
        float hn0 = zz.x * hp.x + (1.f - zz.x) * g0;
        float hn1 = zz.y * hp.y + (1.f - zz.y) * g1;
        cst8(p.h1f32 + (size_t)((t - 1) & 1) * MBHD + m * HD + j0, pk64(hn0, hn1));
        cst4(p.h116 + (size_t)((t - 1) & 1) * MBHD + m * HD + j0, pk16x2(hn0, hn1));
      }
    }
    gbar(p.bar, w, 2u * t + 1u);
  }
  // Epilogue: final hidden states (both in parity buffer 1 after step 511).
  if (w < MB) {
    const float* h0f = p.h0f32 + MBHD;
    const float* h1f = p.h1f32 + MBHD;
#pragma unroll
    for (int it = 0; it < 4; ++it) {
      int i2 = (it * 256 + tid) * 2;  // 0..2046 step 2 over 2*HD
      float2 v = (i2 < HD) ? upk64(cld8(&h0f[w * HD + i2]))
                           : upk64(cld8(&h1f[w * HD + (i2 - HD)]));
      *(float2*)&p.out[(size_t)MB * SEQ * OD + (size_t)w * 2 * HD + i2] = v;
    }
  }
}

// ---------------- prologue kernels ----------------

__global__ void convx_k(const float* __restrict__ x, u16* __restrict__ X16) {
  size_t i = (size_t)blockIdx.x * 256 + threadIdx.x;
  const float4* s = (const float4*)x + i * 2;
  float4 a = s[0], b = s[1];
  u16 o[8];
  o[0] = f16b(a.x); o[1] = f16b(a.y); o[2] = f16b(a.z); o[3] = f16b(a.w);
  o[4] = f16b(b.x); o[5] = f16b(b.y); o[6] = f16b(b.z); o[7] = f16b(b.w);
  *(int4*)(X16 + i * 8) = *(const int4*)o;
}

__global__ void inith_k(const float* __restrict__ h0in,
                        float* h0f32, float* h1f32, u16* h016, u16* h116) {
  int idx = blockIdx.x * 256 + threadIdx.x;  // [b][l][h], 65536
  float v = h0in[idx];
  int b = idx >> 11, rem = idx & 2047;
  int l = rem >> 10, h = rem & 1023;
  int o = MBHD + b * HD + h;                 // parity buffer 1
  if (l == 0) { h0f32[o] = v; h016[o] = f16b(v); }
  else        { h1f32[o] = v; h116[o] = f16b(v); }
}

// Build [N][K] fp16 transposed weight blocks (K = concat Wx rows then Wh rows).
__global__ void wtrans_k(const float* __restrict__ Wx0, const float* __restrict__ Wh0,
                         const float* __restrict__ Wx1, const float* __restrict__ Wh1,
                         const float* __restrict__ Wy,
                         u16* A0, u16* B0, u16* C1, u16* D1, u16* Y) {
  __shared__ u16 tile[32][34];
  int mid = blockIdx.z;
  int K, N, k1, coloff, ld; const float *b1, *b2; u16* dst;
  if (mid == 0)      { K = 1280; N = 2048; k1 = ID; coloff = 0;    ld = 3072; b1 = Wx0; b2 = Wh0; dst = A0; }
  else if (mid == 1) { K = 1280; N = 1024; k1 = ID; coloff = 2048; ld = 3072; b1 = Wx0; b2 = Wh0; dst = B0; }
  else if (mid == 2) { K = 2048; N = 2048; k1 = HD; coloff = 0;    ld = 3072; b1 = Wx1; b2 = Wh1; dst = C1; }
  else if (mid == 3) { K = 2048; N = 1024; k1 = HD; coloff = 2048; ld = 3072; b1 = Wx1; b2 = Wh1; dst = D1; }
  else               { K = 1024; N = 256;  k1 = HD; coloff = 0;    ld = OD;   b1 = Wy;  b2 = Wy;  dst = Y;  }
  int k0 = blockIdx.x << 5, n0 = blockIdx.y << 5;
  if (k0 >= K || n0 >= N) return;
  int tx = threadIdx.x & 31, ty = threadIdx.x >> 5;
#pragma unroll
  for (int i = 0; i < 4; ++i) {
    int kk = (ty << 2) + i, k = k0 + kk;
    int col = coloff + n0 + tx;
    const float* src = (k < k1) ? (b1 + (size_t)k * ld + col)
                                : (b2 + (size_t)(k - k1) * ld + col);
    tile[kk][tx] = f16b(*src);
  }
  __syncthreads();
#pragma unroll
  for (int i = 0; i < 4; ++i) {
    int nn = (ty << 2) + i;
    dst[(size_t)(n0 + nn) * K + k0 + tx] = tile[tx][nn];
  }
}

// ---------------- host launch ----------------

extern "C" void kernel_launch(void* const* d_in, const int* in_sizes, int n_in,
                              void* d_out, int out_size, void* d_ws, size_t ws_size,
                              hipStream_t stream) {
  const float* x    = (const float*)d_in[0];
  const float* h0in = (const float*)d_in[1];
  const float* Wx0  = (const float*)d_in[2];
  const float* Wh0  = (const float*)d_in[3];
  const float* bh0  = (const float*)d_in[4];
  const float* Wx1  = (const float*)d_in[5];
  const float* Wh1  = (const float*)d_in[6];
  const float* bh1  = (const float*)d_in[7];
  const float* Wy   = (const float*)d_in[8];
  const float* by   = (const float*)d_in[9];

  char* ws = (char*)d_ws;
  size_t off = 0;
  auto alloc = [&](size_t bytes) {
    void* pp = ws + off;
    off += (bytes + 255) & ~(size_t)255;
    return pp;
  };
  u16* WtA0 = (u16*)alloc(2048ull * 1280 * 2);
  u16* WtB0 = (u16*)alloc(1024ull * 1280 * 2);
  u16* WtC1 = (u16*)alloc(2048ull * 2048 * 2);
  u16* WtD1 = (u16*)alloc(1024ull * 2048 * 2);
  u16* WtY  = (u16*)alloc(256ull * 1024 * 2);
  u16* X16  = (u16*)alloc((size_t)MB * SEQ * ID * 2);
  u16* h016  = (u16*)alloc(2ull * MBHD * 2);
  u16* h116  = (u16*)alloc(2ull * MBHD * 2);
  u16* rh016 = (u16*)alloc((size_t)MBHD * 2);
  u16* rh116 = (u16*)alloc((size_t)MBHD * 2);
  float* h0f32 = (float*)alloc(2ull * MBHD * 4);
  float* h1f32 = (float*)alloc(2ull * MBHD * 4);
  float* z0    = (float*)alloc((size_t)MBHD * 4);
  float* z1    = (float*)alloc((size_t)MBHD * 4);
  unsigned* bar = (unsigned*)alloc(8192);

  hipMemsetAsync(bar, 0, 8192, stream);
  hipLaunchKernelGGL(convx_k, dim3((MB * SEQ * ID / 8) / 256), dim3(256), 0, stream,
                     x, X16);
  hipLaunchKernelGGL(wtrans_k, dim3(64, 64, 5), dim3(256), 0, stream,
                     Wx0, Wh0, Wx1, Wh1, Wy, WtA0, WtB0, WtC1, WtD1, WtY);
  hipLaunchKernelGGL(inith_k, dim3(65536 / 256), dim3(256), 0, stream,
                     h0in, h0f32, h1f32, h016, h116);

  GruP p;
  p.bh0 = bh0; p.bh1 = bh1; p.by = by;
  p.X16 = X16; p.WtA0 = WtA0; p.WtB0 = WtB0; p.WtC1 = WtC1; p.WtD1 = WtD1; p.WtY = WtY;
  p.h016 = h016; p.h116 = h116; p.rh016 = rh016; p.rh116 = rh116;
  p.h0f32 = h0f32; p.h1f32 = h1f32; p.z0 = z0; p.z1 = z1;
  p.bar = bar;
  p.out = (float*)d_out;

  // Plain launch (round-4 proven): custom barrier, structural 1 block/CU.
  hipLaunchKernelGGL(gru_main, dim3(256), dim3(256), 0, stream, p);
}

// Round 6
// 6863.986 us; speedup vs baseline: 6.3863x; 1.1122x over previous
//
#include <hip/hip_runtime.h>

typedef unsigned short u16;
typedef unsigned long long u64;
typedef _Float16 half8 __attribute__((ext_vector_type(8)));
typedef float f32x4 __attribute__((ext_vector_type(4)));
typedef int i32x4 __attribute__((ext_vector_type(4)));

#define SEQ 512
#define MB 32
#define HD 1024
#define ID 256
#define OD 256
#define MBHD (MB * HD)

__device__ __forceinline__ u16 f16b(float v) {
  union { _Float16 h; u16 u; } cv;
  cv.h = (_Float16)v;
  return cv.u;
}
__device__ __forceinline__ u64 pk64(float a, float b) {
  union { float f[2]; u64 u; } c; c.f[0] = a; c.f[1] = b; return c.u;
}
__device__ __forceinline__ float2 upk64(u64 v) {
  union { u64 u; float2 f; } c; c.u = v; return c.f;
}
__device__ __forceinline__ unsigned pk16x2(float a, float b) {
  union { _Float16 h[2]; unsigned u; } c;
  c.h[0] = (_Float16)a; c.h[1] = (_Float16)b; return c.u;
}

// ---- device(agent)-scope coherent ops: `sc1` = device scope (the exact
// encoding round-4's proven agent-scope atomics used). Stores allocate in
// the MALL (no HBM write-through); loads read at the MALL (cross-XCD safe)
// and coalesce across lanes (round-5 proven).
__device__ __forceinline__ void cst4(void* p, unsigned v) {
  asm volatile("global_store_dword %0, %1, off sc1" :: "v"(p), "v"(v) : "memory");
}
__device__ __forceinline__ void cst8(void* p, u64 v) {
  asm volatile("global_store_dwordx2 %0, %1, off sc1" :: "v"(p), "v"(v) : "memory");
}
__device__ __forceinline__ u64 cld8(const void* p) {
  u64 v;
  asm volatile("global_load_dwordx2 %0, %1, off sc1\n\ts_waitcnt vmcnt(0)"
               : "=&v"(v) : "v"(p) : "memory");
  return v;
}

struct GruP {
  const float *bh0, *bh1, *by;
  const u16 *X16, *WtA0, *WtB0, *WtC1, *WtD1, *WtY;
  u16 *h016, *h116;       // fp16 parity-2 [2][MBHD], coherent both sides
  u16 *rh016, *rh116;     // fp16 [MBHD], coherent both sides
  float *h0f32, *h1f32;   // fp32 parity-2 [2][MBHD], coherent both sides
  unsigned* bar;
  float* out;
};

// Hierarchical grid barrier (round-4/5 proven): 16 groups -> root -> epoch flag.
// Release = vmcnt(0): all prior device-scope stores complete at the MALL.
__device__ __forceinline__ void gbar(unsigned* bar, int w, unsigned ep) {
  asm volatile("s_waitcnt vmcnt(0)" ::: "memory");
  __syncthreads();
  if (threadIdx.x == 0) {
    unsigned tgt = ep * 16u + 15u;
    unsigned old = __hip_atomic_fetch_add(&bar[(w >> 4) << 6], 1u,
                                          __ATOMIC_RELAXED, __HIP_MEMORY_SCOPE_AGENT);
    if (old == tgt) {
      unsigned ro = __hip_atomic_fetch_add(&bar[1024], 1u,
                                           __ATOMIC_RELAXED, __HIP_MEMORY_SCOPE_AGENT);
      if (ro == tgt)
        __hip_atomic_store(&bar[1088], ep + 1u,
                           __ATOMIC_RELAXED, __HIP_MEMORY_SCOPE_AGENT);
    }
    for (int spin = 0; spin < (1 << 16); ++spin) {
      if (__hip_atomic_load(&bar[1088], __ATOMIC_RELAXED,
                            __HIP_MEMORY_SCOPE_AGENT) > ep)
        break;
      __builtin_amdgcn_s_sleep(1);
    }
  }
  __syncthreads();
  asm volatile("" ::: "memory");
}

// Stage the X part (chunks [0,32), K1=256) via cached 16B loads (read-only data).
template <int K>
__device__ __forceinline__ void stage_x(u16* sm, const u16* __restrict__ xrow, int tid) {
#pragma unroll
  for (int it = 0; it < 4; ++it) {
    int i = it * 256 + tid;
    int r = i >> 5, c = i & 31;
    i32x4 v = *(const i32x4*)(xrow + (size_t)r * (SEQ * ID) + (c << 3));
    *(i32x4*)(sm + r * K + ((c ^ (r & 7)) << 3)) = v;
  }
}

// Stage one fp16 [32][1024] dynamic source into LDS chunks [C0, C0+128):
// 16 coherent coalesced 16B loads in flight, ONE vmcnt(0) (single MALL round
// trip). Optional 17th 8B load (hprev preload), issued FIRST (oldest -> done
// at the wait). All loads + wait live in one asm block: no issue/wait split
// hazards (guide rule #18).
template <int K, int C0, bool HP>
__device__ __forceinline__ void stage16(u16* sm, const u16* __restrict__ src,
                                        int tid, const void* hpp, u64& hpv) {
  const int r0 = tid >> 7, q = tid & 127;
  const u16* b = src + (size_t)r0 * HD + (q << 3);
  i32x4 vv[16];
  if constexpr (HP) {
    asm volatile(
        "global_load_dwordx2 %16, %33, off sc1\n\t"
        "global_load_dwordx4 %0, %17, off sc1\n\t"
        "global_load_dwordx4 %1, %18, off sc1\n\t"
        "global_load_dwordx4 %2, %19, off sc1\n\t"
        "global_load_dwordx4 %3, %20, off sc1\n\t"
        "global_load_dwordx4 %4, %21, off sc1\n\t"
        "global_load_dwordx4 %5, %22, off sc1\n\t"
        "global_load_dwordx4 %6, %23, off sc1\n\t"
        "global_load_dwordx4 %7, %24, off sc1\n\t"
        "global_load_dwordx4 %8, %25, off sc1\n\t"
        "global_load_dwordx4 %9, %26, off sc1\n\t"
        "global_load_dwordx4 %10, %27, off sc1\n\t"
        "global_load_dwordx4 %11, %28, off sc1\n\t"
        "global_load_dwordx4 %12, %29, off sc1\n\t"
        "global_load_dwordx4 %13, %30, off sc1\n\t"
        "global_load_dwordx4 %14, %31, off sc1\n\t"
        "global_load_dwordx4 %15, %32, off sc1\n\t"
        "s_waitcnt vmcnt(0)"
        : "=&v"(vv[0]), "=&v"(vv[1]), "=&v"(vv[2]), "=&v"(vv[3]),
          "=&v"(vv[4]), "=&v"(vv[5]), "=&v"(vv[6]), "=&v"(vv[7]),
          "=&v"(vv[8]), "=&v"(vv[9]), "=&v"(vv[10]), "=&v"(vv[11]),
          "=&v"(vv[12]), "=&v"(vv[13]), "=&v"(vv[14]), "=&v"(vv[15]),
          "=&v"(hpv)
        : "v"(b), "v"(b + 2 * HD), "v"(b + 4 * HD), "v"(b + 6 * HD),
          "v"(b + 8 * HD), "v"(b + 10 * HD), "v"(b + 12 * HD), "v"(b + 14 * HD),
          "v"(b + 16 * HD), "v"(b + 18 * HD), "v"(b + 20 * HD), "v"(b + 22 * HD),
          "v"(b + 24 * HD), "v"(b + 26 * HD), "v"(b + 28 * HD), "v"(b + 30 * HD),
          "v"(hpp)
        : "memory");
  } else {
    asm volatile(
        "global_load_dwordx4 %0, %16, off sc1\n\t"
        "global_load_dwordx4 %1, %17, off sc1\n\t"
        "global_load_dwordx4 %2, %18, off sc1\n\t"
        "global_load_dwordx4 %3, %19, off sc1\n\t"
        "global_load_dwordx4 %4, %20, off sc1\n\t"
        "global_load_dwordx4 %5, %21, off sc1\n\t"
        "global_load_dwordx4 %6, %22, off sc1\n\t"
        "global_load_dwordx4 %7, %23, off sc1\n\t"
        "global_load_dwordx4 %8, %24, off sc1\n\t"
        "global_load_dwordx4 %9, %25, off sc1\n\t"
        "global_load_dwordx4 %10, %26, off sc1\n\t"
        "global_load_dwordx4 %11, %27, off sc1\n\t"
        "global_load_dwordx4 %12, %28, off sc1\n\t"
        "global_load_dwordx4 %13, %29, off sc1\n\t"
        "global_load_dwordx4 %14, %30, off sc1\n\t"
        "global_load_dwordx4 %15, %31, off sc1\n\t"
        "s_waitcnt vmcnt(0)"
        : "=&v"(vv[0]), "=&v"(vv[1]), "=&v"(vv[2]), "=&v"(vv[3]),
          "=&v"(vv[4]), "=&v"(vv[5]), "=&v"(vv[6]), "=&v"(vv[7]),
          "=&v"(vv[8]), "=&v"(vv[9]), "=&v"(vv[10]), "=&v"(vv[11]),
          "=&v"(vv[12]), "=&v"(vv[13]), "=&v"(vv[14]), "=&v"(vv[15])
        : "v"(b), "v"(b + 2 * HD), "v"(b + 4 * HD), "v"(b + 6 * HD),
          "v"(b + 8 * HD), "v"(b + 10 * HD), "v"(b + 12 * HD), "v"(b + 14 * HD),
          "v"(b + 16 * HD), "v"(b + 18 * HD), "v"(b + 20 * HD), "v"(b + 22 * HD),
          "v"(b + 24 * HD), "v"(b + 26 * HD), "v"(b + 28 * HD), "v"(b + 30 * HD)
        : "memory");
  }
  const int cq = C0 + q;
#pragma unroll
  for (int u = 0; u < 16; ++u) {
    int r = r0 + 2 * u;
    *(i32x4*)(sm + r * K + ((cq ^ (r & 7)) << 3)) = vv[u];
  }
}

// One wave: partial [32 x 16] over its K-quarter. Weights [N][K] cached (L2).
// Dual accumulator chains (even/odd k-step) halve the dependent-MFMA latency.
template <int K>
__device__ __forceinline__ void mm16(const u16* sm, const u16* __restrict__ Wt,
                                     int n0, int wave, int lane, f32x4& o0, f32x4& o1) {
  constexpr int NST = K >> 7;
  int b = lane >> 4, rr = lane & 15, sw = rr & 7;
  const u16* wrow = Wt + (size_t)(n0 + rr) * K + (b << 3);
  const u16* ar0 = sm + rr * K;
  const u16* ar1 = sm + (16 + rr) * K;
  int kbeg = wave * (K >> 2);
  f32x4 a0 = {0.f, 0.f, 0.f, 0.f}, a1 = {0.f, 0.f, 0.f, 0.f};
  f32x4 c0 = {0.f, 0.f, 0.f, 0.f}, c1 = {0.f, 0.f, 0.f, 0.f};
#pragma unroll
  for (int s = 0; s < NST; s += 2) {
    {
      int k0 = kbeg + (s << 5);
      int ci = (k0 >> 3) + b;
      half8 A0 = *(const half8*)(ar0 + ((ci ^ sw) << 3));
      half8 A1 = *(const half8*)(ar1 + ((ci ^ sw) << 3));
      half8 Bf = *(const half8*)(wrow + k0);
      a0 = __builtin_amdgcn_mfma_f32_16x16x32_f16(A0, Bf, a0, 0, 0, 0);
      a1 = __builtin_amdgcn_mfma_f32_16x16x32_f16(A1, Bf, a1, 0, 0, 0);
    }
    {
      int k0 = kbeg + ((s + 1) << 5);
      int ci = (k0 >> 3) + b;
      half8 A0 = *(const half8*)(ar0 + ((ci ^ sw) << 3));
      half8 A1 = *(const half8*)(ar1 + ((ci ^ sw) << 3));
      half8 Bf = *(const half8*)(wrow + k0);
      c0 = __builtin_amdgcn_mfma_f32_16x16x32_f16(A0, Bf, c0, 0, 0, 0);
      c1 = __builtin_amdgcn_mfma_f32_16x16x32_f16(A1, Bf, c1, 0, 0, 0);
    }
  }
  o0 = a0 + c0;
  o1 = a1 + c1;
}

__global__ void __launch_bounds__(256, 1) gru_main(GruP p) {
  __shared__ __align__(16) u16 sm[MB * 2048];  // 128 KB staged input
  __shared__ float psum[4][MB][16];            // 8 KB cross-wave partials
  const int w = blockIdx.x, tid = threadIdx.x;
  const int wave = tid >> 6, lane = tid & 63;
  const int m = tid >> 3, jc = (tid & 7) << 1;
  const int cc = lane & 15, rb = (lane >> 4) << 2;

  for (int t = 0; t <= SEQ + 1; ++t) {
    float zc0 = 0.f, zc1 = 0.f;   // z-gate register carry (alpha -> beta)
    float2 hpc = {0.f, 0.f};      // hprev register carry (alpha -> beta)
    // ============ tick ALPHA: z,r gates (L0 step t | L1 step t-1) ============
    if (w < 128) {
      if (t < SEQ) {
        int n0 = w << 4;
        int j0 = n0 + jc;
        const float* hprev = p.h0f32 + (size_t)((t + 1) & 1) * MBHD;
        int pidx = m * HD + ((w < 64) ? j0 : (j0 - HD));
        stage_x<1280>(sm, p.X16 + (size_t)t * ID, tid);
        u64 hpv;
        stage16<1280, 32, true>(sm, p.h016 + (size_t)((t + 1) & 1) * MBHD, tid,
                                &hprev[pidx], hpv);
        __syncthreads();
        f32x4 a0, a1;
        mm16<1280>(sm, p.WtA0, n0, wave, lane, a0, a1);
#pragma unroll
        for (int i = 0; i < 4; ++i) {
          psum[wave][rb + i][cc] = a0[i];
          psum[wave][16 + rb + i][cc] = a1[i];
        }
        __syncthreads();
        float2 s0 = *(const float2*)&psum[0][m][jc];
        float2 s1v = *(const float2*)&psum[1][m][jc];
        float2 s2v = *(const float2*)&psum[2][m][jc];
        float2 s3v = *(const float2*)&psum[3][m][jc];
        float v0 = s0.x + s1v.x + s2v.x + s3v.x + p.bh0[j0];
        float v1 = s0.y + s1v.y + s2v.y + s3v.y + p.bh0[j0 + 1];
        v0 = 1.f / (1.f + __expf(-v0));
        v1 = 1.f / (1.f + __expf(-v1));
        float2 hp = upk64(hpv);
        if (w < 64) {
          zc0 = v0; zc1 = v1; hpc = hp;            // carry to beta in registers
        } else {
          cst4(p.rh016 + pidx, pk16x2(v0 * hp.x, v1 * hp.y));
        }
      }
    } else {
      if (t >= 1 && t <= SEQ) {
        int n0 = (w - 128) << 4;
        int j0 = n0 + jc;
        const float* hprev = p.h1f32 + (size_t)(t & 1) * MBHD;
        int pidx = m * HD + ((w < 192) ? j0 : (j0 - HD));
        u64 hpv, dummy;
        stage16<2048, 0, true>(sm, p.h016 + (size_t)((t - 1) & 1) * MBHD, tid,
                               &hprev[pidx], hpv);
        stage16<2048, 128, false>(sm, p.h116 + (size_t)(t & 1) * MBHD, tid,
                                  nullptr, dummy);
        __syncthreads();
        f32x4 a0, a1;
        mm16<2048>(sm, p.WtC1, n0, wave, lane, a0, a1);
#pragma unroll
        for (int i = 0; i < 4; ++i) {
          psum[wave][rb + i][cc] = a0[i];
          psum[wave][16 + rb + i][cc] = a1[i];
        }
        __syncthreads();
        float2 s0 = *(const float2*)&psum[0][m][jc];
        float2 s1v = *(const float2*)&psum[1][m][jc];
        float2 s2v = *(const float2*)&psum[2][m][jc];
        float2 s3v = *(const float2*)&psum[3][m][jc];
        float v0 = s0.x + s1v.x + s2v.x + s3v.x + p.bh1[j0];
        float v1 = s0.y + s1v.y + s2v.y + s3v.y + p.bh1[j0 + 1];
        v0 = 1.f / (1.f + __expf(-v0));
        v1 = 1.f / (1.f + __expf(-v1));
        float2 hp = upk64(hpv);
        if (w < 192) {
          zc0 = v0; zc1 = v1; hpc = hp;            // carry to beta in registers
        } else {
          cst4(p.rh116 + pidx, pk16x2(v0 * hp.x, v1 * hp.y));
        }
      }
    }
    gbar(p.bar, w, 2u * t);
    // ============ tick BETA: g + h update (L0 t | L1 t-1), y(t-2) ============
    if (w < 64) {
      if (t < SEQ) {
        int n0 = w << 4;
        int j0 = n0 + jc;
        stage_x<1280>(sm, p.X16 + (size_t)t * ID, tid);
        u64 dummy;
        stage16<1280, 32, false>(sm, p.rh016, tid, nullptr, dummy);
        __syncthreads();
        f32x4 a0, a1;
        mm16<1280>(sm, p.WtB0, n0, wave, lane, a0, a1);
#pragma unroll
        for (int i = 0; i < 4; ++i) {
          psum[wave][rb + i][cc] = a0[i];
          psum[wave][16 + rb + i][cc] = a1[i];
        }
        __syncthreads();
        float2 s0 = *(const float2*)&psum[0][m][jc];
        float2 s1v = *(const float2*)&psum[1][m][jc];
        float2 s2v = *(const float2*)&psum[2][m][jc];
        float2 s3v = *(const float2*)&psum[3][m][jc];
        float v0 = s0.x + s1v.x + s2v.x + s3v.x + p.bh0[2 * HD + j0];
        float v1 = s0.y + s1v.y + s2v.y + s3v.y + p.bh0[2 * HD + j0 + 1];
        float g0 = tanhf(v0), g1 = tanhf(v1);
        float hn0 = zc0 * hpc.x + (1.f - zc0) * g0;
        float hn1 = zc1 * hpc.y + (1.f - zc1) * g1;
        cst8(p.h0f32 + (size_t)(t & 1) * MBHD + m * HD + j0, pk64(hn0, hn1));
        cst4(p.h016 + (size_t)(t & 1) * MBHD + m * HD + j0, pk16x2(hn0, hn1));
      }
    } else if (w < 80) {
      if (t >= 2) {
        int n0 = (w - 64) << 4;
        int j0 = n0 + jc;
        u64 dummy;
        stage16<1024, 0, false>(sm, p.h116 + (size_t)(t & 1) * MBHD, tid,
                                nullptr, dummy);
        __syncthreads();
        f32x4 a0, a1;
        mm16<1024>(sm, p.WtY, n0, wave, lane, a0, a1);
#pragma unroll
        for (int i = 0; i < 4; ++i) {
          psum[wave][rb + i][cc] = a0[i];
          psum[wave][16 + rb + i][cc] = a1[i];
        }
        __syncthreads();
        float2 s0 = *(const float2*)&psum[0][m][jc];
        float2 s1v = *(const float2*)&psum[1][m][jc];
        float2 s2v = *(const float2*)&psum[2][m][jc];
        float2 s3v = *(const float2*)&psum[3][m][jc];
        float v0 = s0.x + s1v.x + s2v.x + s3v.x + p.by[j0];
        float v1 = s0.y + s1v.y + s2v.y + s3v.y + p.by[j0 + 1];
        *(float2*)&p.out[((size_t)m * SEQ + (t - 2)) * OD + j0] = make_float2(v0, v1);
      }
    } else if (w >= 128 && w < 192) {
      if (t >= 1 && t <= SEQ) {
        int n0 = (w - 128) << 4;
        int j0 = n0 + jc;
        u64 dummy;
        stage16<2048, 0, false>(sm, p.h016 + (size_t)((t - 1) & 1) * MBHD, tid,
                                nullptr, dummy);
        stage16<2048, 128, false>(sm, p.rh116, tid, nullptr, dummy);
        __syncthreads();
        f32x4 a0, a1;
        mm16<2048>(sm, p.WtD1, n0, wave, lane, a0, a1);
#pragma unroll
        for (int i = 0; i < 4; ++i) {
          psum[wave][rb + i][cc] = a0[i];
          psum[wave][16 + rb + i][cc] = a1[i];
        }
        __syncthreads();
        float2 s0 = *(const float2*)&psum[0][m][jc];
        float2 s1v = *(const float2*)&psum[1][m][jc];
        float2 s2v = *(const float2*)&psum[2][m][jc];
        float2 s3v = *(const float2*)&psum[3][m][jc];
        float v0 = s0.x + s1v.x + s2v.x + s3v.x + p.bh1[2 * HD + j0];
        float v1 = s0.y + s1v.y + s2v.y + s3v.y + p.bh1[2 * HD + j0 + 1];
        float g0 = tanhf(v0), g1 = tanhf(v1);
        float hn0 = zc0 * hpc.x + (1.f - zc0) * g0;
        float hn1 = zc1 * hpc.y + (1.f - zc1) * g1;
        cst8(p.h1f32 + (size_t)((t - 1) & 1) * MBHD + m * HD + j0, pk64(hn0, hn1));
        cst4(p.h116 + (size_t)((t - 1) & 1) * MBHD + m * HD + j0, pk16x2(hn0, hn1));
      }
    }
    gbar(p.bar, w, 2u * t + 1u);
  }
  // Epilogue: final hidden states (both in parity buffer 1 after step 511).
  if (w < MB) {
    const float* h0f = p.h0f32 + MBHD;
    const float* h1f = p.h1f32 + MBHD;
#pragma unroll
    for (int it = 0; it < 4; ++it) {
      int i2 = (it * 256 + tid) * 2;  // 0..2046 step 2 over 2*HD
      float2 v = (i2 < HD) ? upk64(cld8(&h0f[w * HD + i2]))
                           : upk64(cld8(&h1f[w * HD + (i2 - HD)]));
      *(float2*)&p.out[(size_t)MB * SEQ * OD + (size_t)w * 2 * HD + i2] = v;
    }
  }
}

// ---------------- prologue kernels ----------------

__global__ void convx_k(const float* __restrict__ x, u16* __restrict__ X16) {
  size_t i = (size_t)blockIdx.x * 256 + threadIdx.x;
  const float4* s = (const float4*)x + i * 2;
  float4 a = s[0], b = s[1];
  u16 o[8];
  o[0] = f16b(a.x); o[1] = f16b(a.y); o[2] = f16b(a.z); o[3] = f16b(a.w);
  o[4] = f16b(b.x); o[5] = f16b(b.y); o[6] = f16b(b.z); o[7] = f16b(b.w);
  *(int4*)(X16 + i * 8) = *(const int4*)o;
}

__global__ void inith_k(const float* __restrict__ h0in,
                        float* h0f32, float* h1f32, u16* h016, u16* h116) {
  int idx = blockIdx.x * 256 + threadIdx.x;  // [b][l][h], 65536
  float v = h0in[idx];
  int b = idx >> 11, rem = idx & 2047;
  int l = rem >> 10, h = rem & 1023;
  int o = MBHD + b * HD + h;                 // parity buffer 1
  if (l == 0) { h0f32[o] = v; h016[o] = f16b(v); }
  else        { h1f32[o] = v; h116[o] = f16b(v); }
}

// Build [N][K] fp16 transposed weight blocks (K = concat Wx rows then Wh rows).
__global__ void wtrans_k(const float* __restrict__ Wx0, const float* __restrict__ Wh0,
                         const float* __restrict__ Wx1, const float* __restrict__ Wh1,
                         const float* __restrict__ Wy,
                         u16* A0, u16* B0, u16* C1, u16* D1, u16* Y) {
  __shared__ u16 tile[32][34];
  int mid = blockIdx.z;
  int K, N, k1, coloff, ld; const float *b1, *b2; u16* dst;
  if (mid == 0)      { K = 1280; N = 2048; k1 = ID; coloff = 0;    ld = 3072; b1 = Wx0; b2 = Wh0; dst = A0; }
  else if (mid == 1) { K = 1280; N = 1024; k1 = ID; coloff = 2048; ld = 3072; b1 = Wx0; b2 = Wh0; dst = B0; }
  else if (mid == 2) { K = 2048; N = 2048; k1 = HD; coloff = 0;    ld = 3072; b1 = Wx1; b2 = Wh1; dst = C1; }
  else if (mid == 3) { K = 2048; N = 1024; k1 = HD; coloff = 2048; ld = 3072; b1 = Wx1; b2 = Wh1; dst = D1; }
  else               { K = 1024; N = 256;  k1 = HD; coloff = 0;    ld = OD;   b1 = Wy;  b2 = Wy;  dst = Y;  }
  int k0 = blockIdx.x << 5, n0 = blockIdx.y << 5;
  if (k0 >= K || n0 >= N) return;
  int tx = threadIdx.x & 31, ty = threadIdx.x >> 5;
#pragma unroll
  for (int i = 0; i < 4; ++i) {
    int kk = (ty << 2) + i, k = k0 + kk;
    int col = coloff + n0 + tx;
    const float* src = (k < k1) ? (b1 + (size_t)k * ld + col)
                                : (b2 + (size_t)(k - k1) * ld + col);
    tile[kk][tx] = f16b(*src);
  }
  __syncthreads();
#pragma unroll
  for (int i = 0; i < 4; ++i) {
    int nn = (ty << 2) + i;
    dst[(size_t)(n0 + nn) * K + k0 + tx] = tile[tx][nn];
  }
}

// ---------------- host launch ----------------

extern "C" void kernel_launch(void* const* d_in, const int* in_sizes, int n_in,
                              void* d_out, int out_size, void* d_ws, size_t ws_size,
                              hipStream_t stream) {
  const float* x    = (const float*)d_in[0];
  const float* h0in = (const float*)d_in[1];
  const float* Wx0  = (const float*)d_in[2];
  const float* Wh0  = (const float*)d_in[3];
  const float* bh0  = (const float*)d_in[4];
  const float* Wx1  = (const float*)d_in[5];
  const float* Wh1  = (const float*)d_in[6];
  const float* bh1  = (const float*)d_in[7];
  const float* Wy   = (const float*)d_in[8];
  const float* by   = (const float*)d_in[9];

  char* ws = (char*)d_ws;
  size_t off = 0;
  auto alloc = [&](size_t bytes) {
    void* pp = ws + off;
    off += (bytes + 255) & ~(size_t)255;
    return pp;
  };
  u16* WtA0 = (u16*)alloc(2048ull * 1280 * 2);
  u16* WtB0 = (u16*)alloc(1024ull * 1280 * 2);
  u16* WtC1 = (u16*)alloc(2048ull * 2048 * 2);
  u16* WtD1 = (u16*)alloc(1024ull * 2048 * 2);
  u16* WtY  = (u16*)alloc(256ull * 1024 * 2);
  u16* X16  = (u16*)alloc((size_t)MB * SEQ * ID * 2);
  u16* h016  = (u16*)alloc(2ull * MBHD * 2);
  u16* h116  = (u16*)alloc(2ull * MBHD * 2);
  u16* rh016 = (u16*)alloc((size_t)MBHD * 2);
  u16* rh116 = (u16*)alloc((size_t)MBHD * 2);
  float* h0f32 = (float*)alloc(2ull * MBHD * 4);
  float* h1f32 = (float*)alloc(2ull * MBHD * 4);
  unsigned* bar = (unsigned*)alloc(8192);

  hipMemsetAsync(bar, 0, 8192, stream);
  hipLaunchKernelGGL(convx_k, dim3((MB * SEQ * ID / 8) / 256), dim3(256), 0, stream,
                     x, X16);
  hipLaunchKernelGGL(wtrans_k, dim3(64, 64, 5), dim3(256), 0, stream,
                     Wx0, Wh0, Wx1, Wh1, Wy, WtA0, WtB0, WtC1, WtD1, WtY);
  hipLaunchKernelGGL(inith_k, dim3(65536 / 256), dim3(256), 0, stream,
                     h0in, h0f32, h1f32, h016, h116);

  GruP p;
  p.bh0 = bh0; p.bh1 = bh1; p.by = by;
  p.X16 = X16; p.WtA0 = WtA0; p.WtB0 = WtB0; p.WtC1 = WtC1; p.WtD1 = WtD1; p.WtY = WtY;
  p.h016 = h016; p.h116 = h116; p.rh016 = rh016; p.rh116 = rh116;
  p.h0f32 = h0f32; p.h1f32 = h1f32;
  p.bar = bar;
  p.out = (float*)d_out;

  // Plain launch (round-4/5 proven): custom barrier, structural 1 block/CU.
  hipLaunchKernelGGL(gru_main, dim3(256), dim3(256), 0, stream, p);
}